// Round 6
// baseline (108.306 us; speedup 1.0000x reference)
//
#include <hip/hip_runtime.h>
#include <hip/hip_bf16.h>

// GruDirection3d forward, d1=d2=d3=1. B=2, C=96, D=H=W=32.
// out[b,c,d,y,x] = z*h_tilde + (1-z)*out[b,c,d-1,y-1,x-1], border = h0.
//
// R6: async-DMA plane wavefront. ONE WAVE per slab (192 blocks x 64 thr).
// z/h_tilde planes are DMA'd global->LDS with global_load_lds (width 16)
// into a 6-slot ring, prefetch distance 5 planes; consumption is gated by
// manual fine-grained `s_waitcnt vmcnt(N)` (8 DMAs + 4 stores per step are
// accounted in N; never vmcnt(0)). The compiler cannot sink these loads —
// R2/R4/R5 all plateaued at ~2000 cyc/step because register prefetch got
// scheduled next to its use, exposing full HBM latency serially.
// The DP h-plane lives in a border-padded LDS buffer (stride 33, row 0 and
// col 0 pre-filled with h0 -> no border conditionals; <=2-way banks = free).
// Single wave => no s_barrier at all; wave_barrier() pins cross-lane LDS
// ordering against compiler reordering (zero HW cost).

#define NPLANE 32
#define PITCH  33            // padded h-buffer row stride

__device__ __forceinline__ void dma16(const float* gp, float* lp) {
    __builtin_amdgcn_global_load_lds(
        (const __attribute__((address_space(1))) void*)gp,
        (__attribute__((address_space(3))) void*)lp, 16, 0, 0);
}

#define WAITV(N) asm volatile("s_waitcnt vmcnt(" #N ")" ::: "memory")

__global__ __launch_bounds__(64) void gru3d_dma(
    const float* __restrict__ zg,
    const float* __restrict__ tg,
    const float* __restrict__ h0p,
    float* __restrict__ og)
{
    __shared__ float rz[6][1024];          // z ring: 6 planes
    __shared__ float rt[6][1024];          // h_tilde ring
    __shared__ float hb[2][PITCH * 33];    // padded h planes (double buffer)

    const int L  = threadIdx.x;            // 0..63
    const int bc = blockIdx.x;             // 0..191
    const int u  = L >> 3;                 // row-in-group 0..7
    const int x0 = (L & 7) * 4;            // column start 0,4,..,28
    const float h0 = h0p[0];

    const size_t slab = (size_t)bc * (NPLANE * 1024);
    const float* zb = zg + slab;
    const float* tb = tg + slab;
    float4*      ov = (float4*)(og + slab);

    // Pre-fill h0 border (row 0 and col 0 of both h buffers). Logical (y,x)
    // lives at (y+1)*PITCH + (x+1); borders are never overwritten.
    for (int j = L; j < 33; j += 64) { hb[0][j] = h0; hb[1][j] = h0; }
    for (int i = L; i < 33; i += 64) { hb[0][i * PITCH] = h0; hb[1][i * PITCH] = h0; }

    auto issue_plane = [&](int p) {
        const float* zp = zb + p * 1024 + L * 4;
        const float* tp = tb + p * 1024 + L * 4;
        float* rzs = &rz[p % 6][0];
        float* rts = &rt[p % 6][0];
        #pragma unroll
        for (int c = 0; c < 4; ++c) {      // 4 chunks x 1KB per tensor
            dma16(zp + c * 256, rzs + c * 256);
            dma16(tp + c * 256, rts + c * 256);
        }
    };

    auto consume = [&](int d) {
        const float4* zs = (const float4*)(&rz[d % 6][0]);
        const float4* ts = (const float4*)(&rt[d % 6][0]);
        const float*  pb = hb[(d + 1) & 1];   // previous plane
        float*        cb = hb[d & 1];         // current plane
        float4 outv[4];
        #pragma unroll
        for (int c = 0; c < 4; ++c) {
            float4 zq = zs[c * 64 + L];       // ds_read_b128, conflict-free
            float4 tq = ts[c * 64 + L];
            const int r = c * 8 + u;          // this lane's row for chunk c
            float pv0, pv1, pv2, pv3;
            if (d == 0) {
                pv0 = pv1 = pv2 = pv3 = h0;   // predecessor plane = border
            } else {                          // prev at (r-1, x0-1..x0+2)
                pv0 = pb[r * PITCH + x0 + 0];
                pv1 = pb[r * PITCH + x0 + 1];
                pv2 = pb[r * PITCH + x0 + 2];
                pv3 = pb[r * PITCH + x0 + 3];
            }
            float4 o;
            o.x = zq.x * tq.x + (1.0f - zq.x) * pv0;
            o.y = zq.y * tq.y + (1.0f - zq.y) * pv1;
            o.z = zq.z * tq.z + (1.0f - zq.z) * pv2;
            o.w = zq.w * tq.w + (1.0f - zq.w) * pv3;
            cb[(r + 1) * PITCH + x0 + 1] = o.x;
            cb[(r + 1) * PITCH + x0 + 2] = o.y;
            cb[(r + 1) * PITCH + x0 + 3] = o.z;
            cb[(r + 1) * PITCH + x0 + 4] = o.w;
            outv[c] = o;
        }
        #pragma unroll
        for (int c = 0; c < 4; ++c)
            ov[d * 256 + c * 64 + L] = outv[c];   // coalesced 1KB per chunk
        __builtin_amdgcn_wave_barrier();          // pin LDS order across steps
    };

    // Prologue: planes 0..4 in flight (5 x 8 = 40 vmcnt ops).
    issue_plane(0); issue_plane(1); issue_plane(2); issue_plane(3); issue_plane(4);

    // Per-step: issue plane d+5, wait until plane d's 8 DMAs retired.
    // N_d = ops-in-FIFO after plane d's batch at the wait point
    //     = 40+4d (d<5), 60 (5<=d<=26), 268-8d (d>=27).  All < 64.
    #define RND(d, N) do { if ((d) + 5 < NPLANE) issue_plane((d) + 5); \
                           WAITV(N); consume(d); } while (0)
    RND(0,40);  RND(1,44);  RND(2,48);  RND(3,52);  RND(4,56);
    RND(5,60);  RND(6,60);  RND(7,60);  RND(8,60);  RND(9,60);
    RND(10,60); RND(11,60); RND(12,60); RND(13,60); RND(14,60);
    RND(15,60); RND(16,60); RND(17,60); RND(18,60); RND(19,60);
    RND(20,60); RND(21,60); RND(22,60); RND(23,60); RND(24,60);
    RND(25,60); RND(26,60);
    RND(27,52); RND(28,44); RND(29,36); RND(30,28); RND(31,20);
    #undef RND
}

extern "C" void kernel_launch(void* const* d_in, const int* in_sizes, int n_in,
                              void* d_out, int out_size, void* d_ws, size_t ws_size,
                              hipStream_t stream) {
    const float* z  = (const float*)d_in[0];
    const float* ht = (const float*)d_in[1];
    const float* h0 = (const float*)d_in[2];
    float* out      = (float*)d_out;

    const int BC = 2 * 96;                 // 192 slabs, one wave each
    gru3d_dma<<<dim3(BC), dim3(64), 0, stream>>>(z, ht, h0, out);
}

// Round 7
// 104.299 us; speedup vs baseline: 1.0384x; 1.0384x over previous
//
#include <hip/hip_runtime.h>
#include <hip/hip_bf16.h>

// GruDirection3d forward, d1=d2=d3=1. B=2, C=96, D=H=W=32.
// out[b,c,d,y,x] = z*h_tilde + (1-z)*out[b,c,d-1,y-1,x-1], border = h0.
//
// R7 = R6's async DMA ring + R2's multi-wave TLP, without either's flaw:
//   192 blocks x 256 thr (4 waves). Wave w owns rows [8w, 8w+8) of every
//   plane: it DMAs its own 1KB z + 1KB t slice per plane (global_load_lds
//   width 16) into a 6-slot LDS ring and gates consumption with per-wave
//   `s_waitcnt vmcnt(N)` (stores counted; in-order retirement). The DP
//   h-plane crosses waves via LDS with an lgkmcnt-ONLY barrier, so the
//   5-plane-deep DMA pipeline survives every barrier (no vmcnt(0) drain —
//   the R2 killer). 4 waves/CU hide LDS latency (the R6 killer).
// h-buffer: padded pitch 33, row 0/col 0 prefilled with h0 (no border
// conditionals); both buffers fully prefilled with h0 so d=0 needs no
// special case. <=2-way LDS bank aliasing everywhere (free on gfx950).

#define NPLANE 32
#define PITCH  33

__device__ __forceinline__ void dma16(const float* gp, float* lp) {
    __builtin_amdgcn_global_load_lds(
        (const __attribute__((address_space(1))) void*)gp,
        (__attribute__((address_space(3))) void*)lp, 16, 0, 0);
}

#define WAITV(N) asm volatile("s_waitcnt vmcnt(" #N ")" ::: "memory")
#define BARL()   asm volatile("s_waitcnt lgkmcnt(0)\n\ts_barrier" ::: "memory")

__global__ __launch_bounds__(256) void gru3d_dma4(
    const float* __restrict__ zg,
    const float* __restrict__ tg,
    const float* __restrict__ h0p,
    float* __restrict__ og)
{
    __shared__ float rz[6][1024];          // z ring, 6 planes
    __shared__ float rt[6][1024];          // h_tilde ring
    __shared__ float hb[2][PITCH * 33];    // padded h planes (double buffer)

    const int tid = threadIdx.x;
    const int w   = tid >> 6;              // wave 0..3, owns rows 8w..8w+7
    const int l   = tid & 63;
    const int bc  = blockIdx.x;            // 0..191
    const int u   = l >> 3;                // row within wave's band, 0..7
    const int r   = 8 * w + u;             // plane row 0..31
    const int x0  = (l & 7) * 4;           // column start
    const float h0 = h0p[0];

    const size_t slab = (size_t)bc * (NPLANE * 1024);
    const float* zb = zg + slab;
    const float* tb = tg + slab;
    float4*      ov = (float4*)(og + slab);

    // Start the DMA pipeline first: planes 0..4 (per wave: 2 dma16/plane).
    // Wave w's slice = bytes [w*1024, w*1024+1024) of each 4KB plane;
    // LDS dest = wave-uniform base + lane*16 (matches the HW scatter rule).
    #define ISSUE(p) do {                                            \
        const int _s = (p) % 6;                                      \
        dma16(zb + (p) * 1024 + w * 256 + l * 4, &rz[_s][w * 256]);  \
        dma16(tb + (p) * 1024 + w * 256 + l * 4, &rt[_s][w * 256]);  \
    } while (0)

    ISSUE(0); ISSUE(1); ISSUE(2); ISSUE(3); ISSUE(4);

    // Prefill both h buffers with h0 (covers d=0 predecessor AND the
    // permanent row-0/col-0 border; interior gets overwritten each step).
    for (int i = tid; i < 2 * PITCH * 33; i += 256)
        ((float*)hb)[i] = h0;
    BARL();

    #define CONSUME(d) do {                                              \
        const float4 zq = ((const float4*)&rz[(d) % 6][0])[w * 64 + l];  \
        const float4 tq = ((const float4*)&rt[(d) % 6][0])[w * 64 + l];  \
        const float* pb = hb[((d) + 1) & 1];                             \
        float*       cb = hb[(d) & 1];                                   \
        float4 o;                                                        \
        o.x = zq.x * tq.x + (1.0f - zq.x) * pb[r * PITCH + x0 + 0];      \
        o.y = zq.y * tq.y + (1.0f - zq.y) * pb[r * PITCH + x0 + 1];      \
        o.z = zq.z * tq.z + (1.0f - zq.z) * pb[r * PITCH + x0 + 2];      \
        o.w = zq.w * tq.w + (1.0f - zq.w) * pb[r * PITCH + x0 + 3];      \
        cb[(r + 1) * PITCH + x0 + 1] = o.x;                              \
        cb[(r + 1) * PITCH + x0 + 2] = o.y;                              \
        cb[(r + 1) * PITCH + x0 + 3] = o.z;                              \
        cb[(r + 1) * PITCH + x0 + 4] = o.w;                              \
        ov[(d) * 256 + w * 64 + l] = o;                                  \
        BARL();                                                          \
    } while (0)

    // Per step: launch plane d+5's DMA, wait plane d's DMA retired
    // (per-wave in-order vmcnt; N = newer ops in FIFO after plane d's
    // last DMA: 2/plane x 5 planes + 1 store/step x 5 = 15 steady).
    #define RND(d, N) do { if ((d) + 5 < NPLANE) ISSUE((d) + 5);  \
                           WAITV(N); CONSUME(d); } while (0)

    RND(0, 10); RND(1, 11); RND(2, 12); RND(3, 13); RND(4, 14);
    RND(5, 15); RND(6, 15); RND(7, 15); RND(8, 15); RND(9, 15);
    RND(10, 15); RND(11, 15); RND(12, 15); RND(13, 15); RND(14, 15);
    RND(15, 15); RND(16, 15); RND(17, 15); RND(18, 15); RND(19, 15);
    RND(20, 15); RND(21, 15); RND(22, 15); RND(23, 15); RND(24, 15);
    RND(25, 15); RND(26, 15);
    RND(27, 13); RND(28, 11); RND(29, 9); RND(30, 7); RND(31, 5);

    #undef RND
    #undef CONSUME
    #undef ISSUE
}

extern "C" void kernel_launch(void* const* d_in, const int* in_sizes, int n_in,
                              void* d_out, int out_size, void* d_ws, size_t ws_size,
                              hipStream_t stream) {
    const float* z  = (const float*)d_in[0];
    const float* ht = (const float*)d_in[1];
    const float* h0 = (const float*)d_in[2];
    float* out      = (float*)d_out;

    const int BC = 2 * 96;                 // 192 slabs, one block (4 waves) each
    gru3d_dma4<<<dim3(BC), dim3(256), 0, stream>>>(z, ht, h0, out);
}